// Round 22
// baseline (51.463 us; speedup 1.0000x reference)
//
#include <hip/hip_runtime.h>
#include <hip/hip_fp16.h>

#define D        128
#define NROWS    100000
#define NET      (NROWS / 16)      // 6250 E-tiles (16 rows each), exact
#define GRID_P   768               // 3 blocks/CU (48 KB LDS each)
#define NWAVES   (GRID_P * 4)      // 3072 grid-striding waves

typedef __attribute__((ext_vector_type(8))) _Float16 f16x8;
typedef __attribute__((ext_vector_type(4))) _Float16 f16x4;
typedef __attribute__((ext_vector_type(4))) float    f32x4;

union F16x8U { _Float16 h[8]; f16x8 v; };
union F16x4U { _Float16 h[4]; f16x4 v; };
union F32x4U { float f[4]; f32x4 v; };

typedef __attribute__((address_space(1))) const void gvoid;
typedef __attribute__((address_space(3))) void       lvoid;

// ---------------------------------------------------------------------------
// Kernel 0 (byte-identical to R21): metric -> fragment-ordered fp16
// B-fragments, NATURAL column mapping: fragment cf, lane-pos p = lane&15
// holds global col c = p*8 + cf, so the C/D epilogue's 8 per-thread values
// are contiguous natural columns. Slot q = (kk*8+cf)*64+lane holds M[k0+j][c],
// k0 = kk*32+(lane>>4)*8 (verified 16x16x32 B-operand layout).
// ---------------------------------------------------------------------------
__global__ __launch_bounds__(256) void convert_M16(
    const float* __restrict__ M, _Float16* __restrict__ mh)
{
    const int q    = blockIdx.x * 256 + threadIdx.x;  // [0, 2048)
    const int kk   = q >> 9;
    const int cf   = (q >> 6) & 7;
    const int lane = q & 63;
    const int col  = (lane & 15) * 8 + cf;            // natural-order mapping
    const int k0   = kk * 32 + (lane >> 4) * 8;

    F16x8U h;
    #pragma unroll
    for (int j = 0; j < 8; ++j) h.h[j] = (_Float16)M[(k0 + j) * D + col];
    *(f16x8*)(mh + q * 8) = h.v;
}

// ---------------------------------------------------------------------------
// Kernel 1 (byte-identical to R21, best measured): E' = E @ M, persistent
// waves, no hot-loop barriers: contiguous f32x4 loads -> cvt fp16 -> XOR-
// swizzled ds_write_b64 into 4KB wave-private scratch -> conflict-free
// ds_read_b128 A-frags -> 32 MFMAs (M fragments in block-shared 32KB LDS)
// -> natural-order f16x8 epilogue stores.
// ---------------------------------------------------------------------------
__global__ __launch_bounds__(256, 3) void gemm_E_pers(
    const float* __restrict__ E, const _Float16* __restrict__ mh,
    _Float16* __restrict__ Ep)
{
    __shared__ _Float16 smM[2048 * 8];   // 32 KB M B-fragment slots
    __shared__ _Float16 scr[4][2048];    // 4 KB per wave

    const int tid  = threadIdx.x;
    const int lane = tid & 63;
    const int w    = tid >> 6;
    const int lrow = lane & 15;
    const int lk   = lane >> 4;

    // Stage M fragments once per block (proven drain).
    #pragma unroll
    for (int it = 0; it < 8; ++it) {
        const int slot = it * 256 + w * 64 + lane;
        __builtin_amdgcn_global_load_lds(
            (gvoid*)(mh + slot * 8), (lvoid*)(smM + (it * 256 + w * 64) * 8),
            16, 0, 0);
    }
    asm volatile("s_waitcnt vmcnt(0)" ::: "memory");
    __syncthreads();

    const f16x8* Bh = (const f16x8*)smM;   // [(kk*8+cf)*64 + lane]
    _Float16*    S  = scr[w];

    const int gw = (int)blockIdx.x * 4 + w;   // 0..3071

    #pragma unroll 1
    for (int t = gw; t < NET; t += NWAVES) {
        // Contiguous loads + cvt + swizzled scratch writes.
        #pragma unroll
        for (int i = 0; i < 8; ++i) {
            const int f   = i * 256 + lane * 4;   // flat float idx in tile
            const int row = f >> 7;
            const int col = f & 127;
            F32x4U v; v.v = *(const f32x4*)(E + (size_t)t * 2048 + f);
            F16x4U h4;
            h4.h[0] = (_Float16)v.f[0]; h4.h[1] = (_Float16)v.f[1];
            h4.h[2] = (_Float16)v.f[2]; h4.h[3] = (_Float16)v.f[3];
            const int tsl = (col >> 3) ^ row;     // XOR swizzle, bijective
            *(f16x4*)(S + row * 128 + tsl * 8 + (col & 7)) = h4.v;
        }
        asm volatile("s_waitcnt lgkmcnt(0)" ::: "memory");
        __builtin_amdgcn_sched_barrier(0);

        f32x4 acc[8];
        #pragma unroll
        for (int cf = 0; cf < 8; ++cf) acc[cf] = (f32x4){0.f, 0.f, 0.f, 0.f};

        #pragma unroll
        for (int kk = 0; kk < 4; ++kk) {
            // A-frag: row lrow, slot (kk*4+lk)^lrow -> cols kk*32+lk*8..+7
            const f16x8 a16 =
                *(const f16x8*)(S + lrow * 128 + ((kk * 4 + lk) ^ lrow) * 8);
            #pragma unroll
            for (int cf = 0; cf < 8; ++cf)
                acc[cf] = __builtin_amdgcn_mfma_f32_16x16x32_f16(
                    a16, Bh[(kk * 8 + cf) * 64 + lane], acc[cf], 0, 0, 0);
        }

        // Epilogue: C/D tile-col = lrow, row = lk*4+i (m89-verified);
        // natural-order f16x8 store per i.
        #pragma unroll
        for (int i = 0; i < 4; ++i) {
            const int ro = t * 16 + lk * 4 + i;
            F16x8U o;
            #pragma unroll
            for (int cf = 0; cf < 8; ++cf) o.h[cf] = (_Float16)acc[cf][i];
            *(f16x8*)(Ep + (size_t)ro * D + lrow * 8) = o.v;
        }
        // Scratch reuse across iterations is safe: per-wave DS ops are
        // in-order and reads above are lgkm-drained before next writes.
    }
}

// ---------------------------------------------------------------------------
// Kernel 2: out[b] = sigmoid(2 * dot(Ep16[xs[b]], N[ys[b]]) - 1) — 4-deep ILP.
// Each 16-lane group handles 4 consecutive outputs: 12 independent vector
// loads (4x f16x8 Ep + 8x f32x4 N) issue before any use; int4 index loads;
// float4 output store. __launch_bounds__(256,4) -> ~128 VGPR, 16 waves/CU.
// Tests whether the fp32-N gather is ILP-bound (helps) or footprint-bound
// (null -> R21 is the plateau).
// ---------------------------------------------------------------------------
__global__ __launch_bounds__(256, 4) void gather_nat4(
    const int* __restrict__ xs, const int* __restrict__ ys,
    const _Float16* __restrict__ Ep, const float* __restrict__ N,
    float* __restrict__ out)
{
    const int tid = threadIdx.x;
    const int o0  = blockIdx.x * 64 + (tid >> 4) * 4;
    const int l   = tid & 15;

    const int4 x4 = *(const int4*)(xs + o0);
    const int4 y4 = *(const int4*)(ys + o0);
    const int xv[4] = {x4.x, x4.y, x4.z, x4.w};
    const int yv[4] = {y4.x, y4.y, y4.z, y4.w};

    // Issue all 12 loads up front (independent).
    f16x8  a[4];
    F32x4U na[4], nb[4];
    #pragma unroll
    for (int q = 0; q < 4; ++q)
        a[q] = *(const f16x8*)(Ep + (size_t)xv[q] * D + l * 8);
    #pragma unroll
    for (int q = 0; q < 4; ++q) {
        na[q].v = *(const f32x4*)(N + (size_t)yv[q] * D + l * 8);
        nb[q].v = *(const f32x4*)(N + (size_t)yv[q] * D + l * 8 + 4);
    }

    float r[4];
    #pragma unroll
    for (int q = 0; q < 4; ++q) {
        float s = 0.f;
        #pragma unroll
        for (int j = 0; j < 4; ++j) {
            s += (float)a[q][j]     * na[q].f[j];
            s += (float)a[q][j + 4] * nb[q].f[j];
        }
        r[q] = s;
    }

    #pragma unroll
    for (int q = 0; q < 4; ++q) {
        r[q] += __shfl_xor(r[q], 1);
        r[q] += __shfl_xor(r[q], 2);
        r[q] += __shfl_xor(r[q], 4);
        r[q] += __shfl_xor(r[q], 8);
    }

    if (l == 0) {
        float4 v;
        v.x = 1.0f / (1.0f + __expf(1.0f - 2.0f * r[0]));
        v.y = 1.0f / (1.0f + __expf(1.0f - 2.0f * r[1]));
        v.z = 1.0f / (1.0f + __expf(1.0f - 2.0f * r[2]));
        v.w = 1.0f / (1.0f + __expf(1.0f - 2.0f * r[3]));
        *(float4*)(out + o0) = v;
    }
}

extern "C" void kernel_launch(void* const* d_in, const int* in_sizes, int n_in,
                              void* d_out, int out_size, void* d_ws, size_t ws_size,
                              hipStream_t stream) {
    const int*   xs     = (const int*)d_in[0];
    const int*   ys     = (const int*)d_in[1];
    const float* metric = (const float*)d_in[2];
    const float* EMBEDM = (const float*)d_in[3];
    const float* NEGEM  = (const float*)d_in[4];
    float*       out    = (float*)d_out;

    const int B = in_sizes[0];  // 262144

    // d_ws layout: Ep16 25.6MB @0, M-fragments 32KB @64MB.
    char* ws = (char*)d_ws;
    _Float16* Ep = (_Float16*)ws;
    _Float16* mh = (_Float16*)(ws + (64u << 20));

    convert_M16<<<8, 256, 0, stream>>>(metric, mh);

    gemm_E_pers<<<GRID_P, 256, 0, stream>>>(EMBEDM, mh, Ep);

    gather_nat4<<<B / 64, 256, 0, stream>>>(xs, ys, Ep, NEGEM, out);
}

// Round 23
// 50.754 us; speedup vs baseline: 1.0140x; 1.0140x over previous
//
#include <hip/hip_runtime.h>
#include <hip/hip_fp16.h>

#define D        128
#define NROWS    100000
#define NET      (NROWS / 16)      // 6250 E-tiles (16 rows each), exact
#define GRID_P   768               // 3 blocks/CU (48 KB LDS each)
#define NWAVES   (GRID_P * 4)      // 3072 grid-striding waves

typedef __attribute__((ext_vector_type(8))) _Float16 f16x8;
typedef __attribute__((ext_vector_type(4))) _Float16 f16x4;
typedef __attribute__((ext_vector_type(4))) float    f32x4;

union F16x8U { _Float16 h[8]; f16x8 v; };
union F16x4U { _Float16 h[4]; f16x4 v; };
union F32x4U { float f[4]; f32x4 v; };

typedef __attribute__((address_space(1))) const void gvoid;
typedef __attribute__((address_space(3))) void       lvoid;

// ---------------------------------------------------------------------------
// Kernel 0 (R21, best measured): metric -> fragment-ordered fp16 B-fragments,
// NATURAL column mapping: fragment cf, lane-pos p = lane&15 holds global col
// c = p*8 + cf, so the C/D epilogue's 8 per-thread values are contiguous
// natural columns. Slot q = (kk*8+cf)*64+lane holds M[k0+j][c],
// k0 = kk*32+(lane>>4)*8 (verified 16x16x32 B-operand layout).
// ---------------------------------------------------------------------------
__global__ __launch_bounds__(256) void convert_M16(
    const float* __restrict__ M, _Float16* __restrict__ mh)
{
    const int q    = blockIdx.x * 256 + threadIdx.x;  // [0, 2048)
    const int kk   = q >> 9;
    const int cf   = (q >> 6) & 7;
    const int lane = q & 63;
    const int col  = (lane & 15) * 8 + cf;            // natural-order mapping
    const int k0   = kk * 32 + (lane >> 4) * 8;

    F16x8U h;
    #pragma unroll
    for (int j = 0; j < 8; ++j) h.h[j] = (_Float16)M[(k0 + j) * D + col];
    *(f16x8*)(mh + q * 8) = h.v;
}

// ---------------------------------------------------------------------------
// Kernel 1 (R21, best measured): E' = E @ M, persistent waves, no hot-loop
// barriers: contiguous f32x4 loads -> cvt fp16 -> XOR-swizzled ds_write_b64
// into 4KB wave-private scratch -> conflict-free ds_read_b128 A-frags ->
// 32 MFMAs (M fragments in block-shared 32KB LDS) -> natural-order f16x8
// epilogue stores.
// ---------------------------------------------------------------------------
__global__ __launch_bounds__(256, 3) void gemm_E_pers(
    const float* __restrict__ E, const _Float16* __restrict__ mh,
    _Float16* __restrict__ Ep)
{
    __shared__ _Float16 smM[2048 * 8];   // 32 KB M B-fragment slots
    __shared__ _Float16 scr[4][2048];    // 4 KB per wave

    const int tid  = threadIdx.x;
    const int lane = tid & 63;
    const int w    = tid >> 6;
    const int lrow = lane & 15;
    const int lk   = lane >> 4;

    // Stage M fragments once per block (proven drain).
    #pragma unroll
    for (int it = 0; it < 8; ++it) {
        const int slot = it * 256 + w * 64 + lane;
        __builtin_amdgcn_global_load_lds(
            (gvoid*)(mh + slot * 8), (lvoid*)(smM + (it * 256 + w * 64) * 8),
            16, 0, 0);
    }
    asm volatile("s_waitcnt vmcnt(0)" ::: "memory");
    __syncthreads();

    const f16x8* Bh = (const f16x8*)smM;   // [(kk*8+cf)*64 + lane]
    _Float16*    S  = scr[w];

    const int gw = (int)blockIdx.x * 4 + w;   // 0..3071

    #pragma unroll 1
    for (int t = gw; t < NET; t += NWAVES) {
        // Contiguous loads + cvt + swizzled scratch writes.
        #pragma unroll
        for (int i = 0; i < 8; ++i) {
            const int f   = i * 256 + lane * 4;   // flat float idx in tile
            const int row = f >> 7;
            const int col = f & 127;
            F32x4U v; v.v = *(const f32x4*)(E + (size_t)t * 2048 + f);
            F16x4U h4;
            h4.h[0] = (_Float16)v.f[0]; h4.h[1] = (_Float16)v.f[1];
            h4.h[2] = (_Float16)v.f[2]; h4.h[3] = (_Float16)v.f[3];
            const int tsl = (col >> 3) ^ row;     // XOR swizzle, bijective
            *(f16x4*)(S + row * 128 + tsl * 8 + (col & 7)) = h4.v;
        }
        asm volatile("s_waitcnt lgkmcnt(0)" ::: "memory");
        __builtin_amdgcn_sched_barrier(0);

        f32x4 acc[8];
        #pragma unroll
        for (int cf = 0; cf < 8; ++cf) acc[cf] = (f32x4){0.f, 0.f, 0.f, 0.f};

        #pragma unroll
        for (int kk = 0; kk < 4; ++kk) {
            // A-frag: row lrow, slot (kk*4+lk)^lrow -> cols kk*32+lk*8..+7
            const f16x8 a16 =
                *(const f16x8*)(S + lrow * 128 + ((kk * 4 + lk) ^ lrow) * 8);
            #pragma unroll
            for (int cf = 0; cf < 8; ++cf)
                acc[cf] = __builtin_amdgcn_mfma_f32_16x16x32_f16(
                    a16, Bh[(kk * 8 + cf) * 64 + lane], acc[cf], 0, 0, 0);
        }

        // Epilogue: C/D tile-col = lrow, row = lk*4+i (m89-verified);
        // natural-order f16x8 store per i.
        #pragma unroll
        for (int i = 0; i < 4; ++i) {
            const int ro = t * 16 + lk * 4 + i;
            F16x8U o;
            #pragma unroll
            for (int cf = 0; cf < 8; ++cf) o.h[cf] = (_Float16)acc[cf][i];
            *(f16x8*)(Ep + (size_t)ro * D + lrow * 8) = o.v;
        }
        // Scratch reuse across iterations is safe: per-wave DS ops are
        // in-order and reads above are lgkm-drained before next writes.
    }
}

// ---------------------------------------------------------------------------
// Kernel 2 (R21, best measured): out[b] = sigmoid(2*dot(Ep16[xs],N[ys]) - 1).
// Ep16 natural order: lane l's f16x8 = cols 8l..8l+7, pairing with N fp32
// cols 8l..8l+7 read as TWO dwordx4 — all-vector loads. 2 outputs per
// lane-group, fp32 accumulate, exact N (no conv_N kernel).
// ---------------------------------------------------------------------------
__global__ __launch_bounds__(256) void gather_nat(
    const int* __restrict__ xs, const int* __restrict__ ys,
    const _Float16* __restrict__ Ep, const float* __restrict__ N,
    float* __restrict__ out)
{
    const int tid = threadIdx.x;
    const int o0  = blockIdx.x * 32 + (tid >> 4) * 2;
    const int l   = tid & 15;

    const int x0 = xs[o0], x1 = xs[o0 + 1];
    const int y0 = ys[o0], y1 = ys[o0 + 1];

    const f16x8 a0 = *(const f16x8*)(Ep + (size_t)x0 * D + l * 8);
    const f16x8 a1 = *(const f16x8*)(Ep + (size_t)x1 * D + l * 8);
    F32x4U n0a, n0b, n1a, n1b;
    n0a.v = *(const f32x4*)(N + (size_t)y0 * D + l * 8);
    n0b.v = *(const f32x4*)(N + (size_t)y0 * D + l * 8 + 4);
    n1a.v = *(const f32x4*)(N + (size_t)y1 * D + l * 8);
    n1b.v = *(const f32x4*)(N + (size_t)y1 * D + l * 8 + 4);

    float r0 = 0.f, r1 = 0.f;
    #pragma unroll
    for (int j = 0; j < 4; ++j) {
        r0 += (float)a0[j]     * n0a.f[j];
        r0 += (float)a0[j + 4] * n0b.f[j];
        r1 += (float)a1[j]     * n1a.f[j];
        r1 += (float)a1[j + 4] * n1b.f[j];
    }

    r0 += __shfl_xor(r0, 1); r1 += __shfl_xor(r1, 1);
    r0 += __shfl_xor(r0, 2); r1 += __shfl_xor(r1, 2);
    r0 += __shfl_xor(r0, 4); r1 += __shfl_xor(r1, 4);
    r0 += __shfl_xor(r0, 8); r1 += __shfl_xor(r1, 8);

    if (l == 0) {
        float2 v;
        v.x = 1.0f / (1.0f + __expf(1.0f - 2.0f * r0));
        v.y = 1.0f / (1.0f + __expf(1.0f - 2.0f * r1));
        *(float2*)(out + o0) = v;
    }
}

extern "C" void kernel_launch(void* const* d_in, const int* in_sizes, int n_in,
                              void* d_out, int out_size, void* d_ws, size_t ws_size,
                              hipStream_t stream) {
    const int*   xs     = (const int*)d_in[0];
    const int*   ys     = (const int*)d_in[1];
    const float* metric = (const float*)d_in[2];
    const float* EMBEDM = (const float*)d_in[3];
    const float* NEGEM  = (const float*)d_in[4];
    float*       out    = (float*)d_out;

    const int B = in_sizes[0];  // 262144

    // d_ws layout: Ep16 25.6MB @0, M-fragments 32KB @64MB.
    char* ws = (char*)d_ws;
    _Float16* Ep = (_Float16*)ws;
    _Float16* mh = (_Float16*)(ws + (64u << 20));

    convert_M16<<<8, 256, 0, stream>>>(metric, mh);

    gemm_E_pers<<<GRID_P, 256, 0, stream>>>(EMBEDM, mh, Ep);

    gather_nat<<<B / 32, 256, 0, stream>>>(xs, ys, Ep, NEGEM, out);
}